// Round 2
// baseline (506.625 us; speedup 1.0000x reference)
//
#include <hip/hip_runtime.h>
#include <hip/hip_bf16.h>

namespace {
constexpr int BS = 32;
constexpr int NQ = 1000;
constexpr int NCLS = 100;
constexpr int TPS = 50;
constexpr int TT = BS * TPS;        // 1600 total targets
constexpr int NQALL = BS * NQ;      // 32000 total queries
}

// ---------------- Kernel 1: focal class-cost table [32000, 100] ----------------
__global__ void hm_class_table(const float* __restrict__ logits,
                               float* __restrict__ table, int n) {
  int i = blockIdx.x * blockDim.x + threadIdx.x;
  if (i >= n) return;
  float x = logits[i];
  float p = 1.0f / (1.0f + expf(-x));
  float neg = 0.75f * (p * p) * (-logf(1.0f - p + 1e-8f));
  float pos = 0.25f * ((1.0f - p) * (1.0f - p)) * (-logf(p + 1e-8f));
  table[i] = pos - neg;
}

// ---------------- Kernel 2: cost matrix + transposed f64 per-batch slice -------
// C[q][t] = |bbox L1| + class_table[q][tgt_ids[t]] + giou  (weights all 1.0)
// cost_t[t][q%NQ] (f64) written only for t in the query's own batch window.
__global__ void hm_cost(const float* __restrict__ pred_boxes,
                        const int* __restrict__ tgt_ids,
                        const float* __restrict__ tgt_bbox,
                        const float* __restrict__ table,
                        float* __restrict__ C,
                        double* __restrict__ cost_t) {
  int q = blockIdx.x;            // global query 0..31999
  int b = q / NQ;
  int qq = q - b * NQ;
  float c1 = pred_boxes[2 * q];
  float w1 = pred_boxes[2 * q + 1];
  float s1 = fminf(fmaxf(c1 - 0.5f * w1, 0.0f), 1.0f);
  float e1 = fminf(fmaxf(c1 + 0.5f * w1, 0.0f), 1.0f);
  float len1 = e1 - s1;
  const float* trow = table + (size_t)q * NCLS;
  float* crow = C + (size_t)q * TT;
  int tlo = b * TPS;
  for (int t = threadIdx.x; t < TT; t += blockDim.x) {
    float c2 = tgt_bbox[2 * t];
    float w2 = tgt_bbox[2 * t + 1];
    float cb = fabsf(c1 - c2) + fabsf(w1 - w2);
    float s2 = fminf(fmaxf(c2 - 0.5f * w2, 0.0f), 1.0f);
    float e2 = fminf(fmaxf(c2 + 0.5f * w2, 0.0f), 1.0f);
    float inter = fmaxf(fminf(e1, e2) - fmaxf(s1, s2), 0.0f);
    float uni = (len1 + (e2 - s2)) - inter;
    float cg = -(inter / uni);
    float cc = trow[tgt_ids[t]];
    float val = (cb + cc) + cg;   // COST_BBOX*bbox + COST_CLASS*class + COST_GIOU*giou
    crow[t] = val;
    if ((unsigned)(t - tlo) < (unsigned)TPS)
      cost_t[(size_t)t * NQ + qq] = (double)val;  // f64 widening, matches np.float64 cast
  }
}

// ---------------- Kernel 3: Jonker-Volgenant LSA, one block per batch ----------
// Exact parallel port of the reference numpy _lsa on cost.T [50, 1000], f64.
__global__ void __launch_bounds__(256) hm_lsa(const double* __restrict__ cost_t,
                                              float* __restrict__ out_idx) {
  __shared__ double v[NQ + 1];
  __shared__ double minv[NQ + 1];
  __shared__ double u[TPS + 1];
  __shared__ int p[NQ + 1];
  __shared__ int way[NQ + 1];
  __shared__ int used[NQ + 1];
  __shared__ double wval[4];
  __shared__ int wjdx[4];
  __shared__ double s_delta, s_ui0;
  __shared__ int s_j0, s_i0, s_brk;

  const double INFD = 1e18;
  int b = blockIdx.x;
  int tid = threadIdx.x;
  const double* cbase = cost_t + (size_t)b * TPS * NQ;

  for (int j = tid; j <= NQ; j += 256) { v[j] = 0.0; p[j] = 0; way[j] = 0; }
  if (tid <= TPS) u[tid] = 0.0;
  __syncthreads();

  for (int i = 1; i <= TPS; ++i) {
    for (int j = tid; j <= NQ; j += 256) { minv[j] = INFD; used[j] = 0; }
    if (tid == 0) { p[0] = i; s_j0 = 0; s_brk = 0; }
    __syncthreads();
    while (true) {
      if (tid == 0) {
        int j0 = s_j0;
        used[j0] = 1;
        int i0 = p[j0];
        s_i0 = i0;
        s_ui0 = u[i0];
      }
      __syncthreads();
      int j0 = s_j0;
      int i0 = s_i0;
      double ui0 = s_ui0;
      const double* row = cbase + (size_t)(i0 - 1) * NQ;
      double bv = INFD;
      int bj = 0x7fffffff;
      #pragma unroll
      for (int k = 0; k < 4; ++k) {
        int j = 1 + tid + k * 256;
        if (j <= NQ && !used[j]) {
          double cur = (row[j - 1] - ui0) - v[j];
          if (cur < minv[j]) { minv[j] = cur; way[j] = j0; }
          double mv = minv[j];
          if (mv < bv || (mv == bv && j < bj)) { bv = mv; bj = j; }
        }
      }
      // wave-level argmin (first-index tie-break), then 4-wave merge
      for (int off = 32; off > 0; off >>= 1) {
        double ov = __shfl_down(bv, off);
        int oj = __shfl_down(bj, off);
        if (ov < bv || (ov == bv && oj < bj)) { bv = ov; bj = oj; }
      }
      if ((tid & 63) == 0) { wval[tid >> 6] = bv; wjdx[tid >> 6] = bj; }
      __syncthreads();
      if (tid == 0) {
        for (int wv = 1; wv < 4; ++wv)
          if (wval[wv] < bv || (wval[wv] == bv && wjdx[wv] < bj)) { bv = wval[wv]; bj = wjdx[wv]; }
        s_delta = bv;   // delta = min over unused minv
        s_j0 = bj;      // j1
      }
      __syncthreads();
      double delta = s_delta;
      int j1 = s_j0;
      if (tid == 0) { u[p[0]] += delta; v[0] -= delta; }   // j=0 is always "used"
      #pragma unroll
      for (int k = 0; k < 4; ++k) {
        int j = 1 + tid + k * 256;
        if (j <= NQ) {
          if (used[j]) { u[p[j]] += delta; v[j] -= delta; }
          else minv[j] -= delta;
        }
      }
      __syncthreads();
      if (tid == 0) { if (p[j1] == 0) s_brk = 1; }
      __syncthreads();
      if (s_brk) break;
    }
    // augment along alternating tree
    if (tid == 0) {
      int j0 = s_j0;
      while (j0 != 0) { int jn = way[j0]; p[j0] = p[jn]; j0 = jn; }
    }
    __syncthreads();
  }
  // extraction: cols sorted ascending => argsort(q_cols) is identity
  if (tid == 0) {
    float* o = out_idx + b * 2 * TPS;
    int k = 0;
    for (int j = 1; j <= NQ; ++j) {
      if (p[j] != 0) { o[k] = (float)(j - 1); o[TPS + k] = (float)(p[j] - 1); ++k; }
    }
  }
}

extern "C" void kernel_launch(void* const* d_in, const int* in_sizes, int n_in,
                              void* d_out, int out_size, void* d_ws, size_t ws_size,
                              hipStream_t stream) {
  const float* logits     = (const float*)d_in[0];  // [32,1000,100]
  const float* pred_boxes = (const float*)d_in[1];  // [32,1000,2]
  const int*   tgt_ids    = (const int*)d_in[2];    // [1600]
  const float* tgt_bbox   = (const float*)d_in[3];  // [1600,2]
  float* out = (float*)d_out;                       // C (51.2M f32) then indices (3200 f32)

  float*  table  = (float*)d_ws;                                        // 12.8 MB
  double* cost_t = (double*)((char*)d_ws + (size_t)NQALL * NCLS * 4);   // 12.8 MB, 8B-aligned

  int ntab = NQALL * NCLS;
  hm_class_table<<<(ntab + 255) / 256, 256, 0, stream>>>(logits, table, ntab);
  hm_cost<<<NQALL, 256, 0, stream>>>(pred_boxes, tgt_ids, tgt_bbox, table, out, cost_t);
  hm_lsa<<<BS, 256, 0, stream>>>(cost_t, out + (size_t)NQALL * TT);
}

// Round 3
// 447.227 us; speedup vs baseline: 1.1328x; 1.1328x over previous
//
#include <hip/hip_runtime.h>
#include <hip/hip_bf16.h>

namespace {
constexpr int BS = 32;
constexpr int NQ = 1000;
constexpr int NCLS = 100;
constexpr int TPS = 50;
constexpr int TT = BS * TPS;        // 1600 total targets
constexpr int NQALL = BS * NQ;      // 32000 total queries
}

// ---------------- Kernel 1: focal class-cost table [32000, 100] ----------------
__global__ void __launch_bounds__(256) hm_class_table(const float* __restrict__ logits,
                                                      float* __restrict__ table) {
  int i = blockIdx.x * 256 + threadIdx.x;
  if (i >= NQALL * NCLS) return;
  float x = logits[i];
  float p = 1.0f / (1.0f + expf(-x));
  float neg = 0.75f * (p * p) * (-logf(1.0f - p + 1e-8f));
  float pos = 0.25f * ((1.0f - p) * (1.0f - p)) * (-logf(p + 1e-8f));
  table[i] = pos - neg;
}

// ---------------- Kernel 2: cost matrix C[q][t], float4 stores, LDS targets ----
__global__ void __launch_bounds__(256) hm_cost(const float* __restrict__ pred_boxes,
                                               const int* __restrict__ tgt_ids,
                                               const float* __restrict__ tgt_bbox,
                                               const float* __restrict__ table,
                                               float* __restrict__ C) {
  __shared__ float s_c2[TT], s_w2[TT], s_s2[TT], s_e2[TT];
  __shared__ int s_id[TT];
  for (int t = threadIdx.x; t < TT; t += 256) {
    float c2 = tgt_bbox[2 * t], w2 = tgt_bbox[2 * t + 1];
    s_c2[t] = c2; s_w2[t] = w2;
    s_s2[t] = fminf(fmaxf(c2 - 0.5f * w2, 0.f), 1.f);
    s_e2[t] = fminf(fmaxf(c2 + 0.5f * w2, 0.f), 1.f);
    s_id[t] = tgt_ids[t];
  }
  __syncthreads();
  const int nvec = NQALL * (TT / 4);                 // 12.8M float4 groups
  for (int vidx = blockIdx.x * 256 + threadIdx.x; vidx < nvec; vidx += gridDim.x * 256) {
    int q = vidx / (TT / 4);
    int t0 = (vidx - q * (TT / 4)) * 4;
    float c1 = pred_boxes[2 * q], w1 = pred_boxes[2 * q + 1];
    float s1 = fminf(fmaxf(c1 - 0.5f * w1, 0.f), 1.f);
    float e1 = fminf(fmaxf(c1 + 0.5f * w1, 0.f), 1.f);
    float len1 = e1 - s1;
    const float* trow = table + (size_t)q * NCLS;
    float4 o;
    float* op = &o.x;
    #pragma unroll
    for (int kk = 0; kk < 4; ++kk) {
      int t = t0 + kk;
      float cb = fabsf(c1 - s_c2[t]) + fabsf(w1 - s_w2[t]);
      float inter = fmaxf(fminf(e1, s_e2[t]) - fmaxf(s1, s_s2[t]), 0.f);
      float uni = (len1 + (s_e2[t] - s_s2[t])) - inter;
      float cg = -(inter / uni);
      op[kk] = (cb + trow[s_id[t]]) + cg;            // (bbox + class) + giou, weights 1
    }
    *reinterpret_cast<float4*>(C + (size_t)q * TT + t0) = o;
  }
}

// ---------------- Kernel 3: transpose the per-batch slices -> ct[b*50+t][q] f32 -
__global__ void __launch_bounds__(256) hm_transpose(const float* __restrict__ C,
                                                    float* __restrict__ ct) {
  int r = blockIdx.x;                 // r = b*TPS + tt  (also the global target col)
  int b = r / TPS;
  const float* src = C + (size_t)b * NQ * TT + r;   // column r of batch b
  float* dst = ct + (size_t)r * NQ;
  for (int q = threadIdx.x; q < NQ; q += 256)
    dst[q] = src[(size_t)q * TT];
}

// ---------------- Kernel 4: single-wave Jonker-Volgenant LSA, 1 wave/batch -----
// Exact port of numpy _lsa on cost.T [50,1000] in f64; cost = (double)ct (f32).
__global__ void __launch_bounds__(64) hm_lsa(const float* __restrict__ ct,
                                             float* __restrict__ out_idx) {
  __shared__ double u[TPS + 1];
  __shared__ int p[NQ + 1];
  __shared__ int way[NQ + 1];

  const double INFD = 1e18;
  int b = blockIdx.x;
  int lane = threadIdx.x;             // 0..63, one wave
  const float* cbase = ct + (size_t)b * TPS * NQ;

  // register state: slot k owns column j = 1 + lane + 64k  (k=15 valid iff lane<40)
  double v[16], minv[16];
  unsigned usedmask;

  #pragma unroll
  for (int k = 0; k < 16; ++k) v[k] = 0.0;
  for (int j = lane; j <= NQ; j += 64) { p[j] = 0; way[j] = 0; }
  if (lane <= TPS) u[lane] = 0.0;
  __syncthreads();

  for (int i = 1; i <= TPS; ++i) {
    #pragma unroll
    for (int k = 0; k < 16; ++k) minv[k] = INFD;
    usedmask = 0u;
    if (lane == 0) p[0] = i;
    int j0 = 0;
    int jfin = 0;
    __syncthreads();
    while (true) {
      // mark used[j0] (register bit in owner lane; j0==0 handled by lane0 below)
      if (j0 > 0) {
        int kk = (j0 - 1) >> 6, ll = (j0 - 1) & 63;
        if (lane == ll) usedmask |= (1u << kk);
      }
      int i0 = p[j0];                 // uniform LDS broadcast
      double ui0 = u[i0];
      const float* row = cbase + (size_t)(i0 - 1) * NQ;
      float rv[16];
      #pragma unroll
      for (int k = 0; k < 16; ++k) {  // unconditional coalesced loads (L2-resident)
        int idx = lane + (k << 6); if (idx > NQ - 1) idx = NQ - 1;
        rv[k] = row[idx];
      }
      double bv = INFD; int bj = 0x7fffffff;
      #pragma unroll
      for (int k = 0; k < 16; ++k) {
        int j = 1 + lane + (k << 6);
        bool valid = (k < 15) | (lane < 40);
        if (valid && !((usedmask >> k) & 1u)) {
          double cur = ((double)rv[k] - ui0) - v[k];
          if (cur < minv[k]) { minv[k] = cur; way[j] = j0; }
          double mv = minv[k];
          if (mv < bv || (mv == bv && j < bj)) { bv = mv; bj = j; }
        }
      }
      // 64-lane butterfly argmin, first-index tie-break; result uniform
      #pragma unroll
      for (int off = 32; off; off >>= 1) {
        double ov = __shfl_xor(bv, off);
        int oj = __shfl_xor(bj, off);
        if (ov < bv || (ov == bv && oj < bj)) { bv = ov; bj = oj; }
      }
      double delta = bv;
      int j1 = bj;
      // updates: used cols (incl. j=0 -> u[p[0]]=u[i]), unused minv
      if (lane == 0) u[i] += delta;
      #pragma unroll
      for (int k = 0; k < 16; ++k) {
        int j = 1 + lane + (k << 6);
        bool valid = (k < 15) | (lane < 40);
        if (!valid) continue;
        if ((usedmask >> k) & 1u) {
          u[p[j]] += delta;           // distinct rows -> race-free
          v[k] -= delta;
        } else {
          minv[k] -= delta;
        }
      }
      __syncthreads();                // single-wave: ~free; orders LDS u writes
      if (p[j1] == 0) { jfin = j1; break; }
      j0 = j1;
    }
    __syncthreads();                  // way[] writes visible
    if (lane == 0) {                  // augment along alternating tree
      int j0a = jfin;
      while (j0a != 0) { int jn = way[j0a]; p[j0a] = p[jn]; j0a = jn; }
    }
    __syncthreads();
  }
  // extraction: ascending j (k-major, lane-minor) == identity argsort
  float* o = out_idx + b * 2 * TPS;
  int total = 0;
  #pragma unroll
  for (int k = 0; k < 16; ++k) {
    int j = 1 + lane + (k << 6);
    bool valid = (k < 15) | (lane < 40);
    int pj = valid ? p[j] : 0;
    bool m = valid && (pj != 0);
    unsigned long long mask = __ballot(m);
    int pos = total + __popcll(mask & ((1ull << lane) - 1ull));
    if (m) { o[pos] = (float)(j - 1); o[TPS + pos] = (float)(pj - 1); }
    total += __popcll(mask);
  }
}

extern "C" void kernel_launch(void* const* d_in, const int* in_sizes, int n_in,
                              void* d_out, int out_size, void* d_ws, size_t ws_size,
                              hipStream_t stream) {
  const float* logits     = (const float*)d_in[0];  // [32,1000,100]
  const float* pred_boxes = (const float*)d_in[1];  // [32,1000,2]
  const int*   tgt_ids    = (const int*)d_in[2];    // [1600]
  const float* tgt_bbox   = (const float*)d_in[3];  // [1600,2]
  float* out = (float*)d_out;                       // C (51.2M f32) then indices

  float* table = (float*)d_ws;                                      // 12.8 MB
  float* ct    = (float*)((char*)d_ws + (size_t)NQALL * NCLS * 4);  // 6.4 MB

  hm_class_table<<<(NQALL * NCLS + 255) / 256, 256, 0, stream>>>(logits, table);
  hm_cost<<<1280, 256, 0, stream>>>(pred_boxes, tgt_ids, tgt_bbox, table, out);
  hm_transpose<<<TT, 256, 0, stream>>>(out, ct);
  hm_lsa<<<BS, 64, 0, stream>>>(ct, out + (size_t)NQALL * TT);
}

// Round 4
// 289.293 us; speedup vs baseline: 1.7512x; 1.5459x over previous
//
#include <hip/hip_runtime.h>
#include <hip/hip_bf16.h>

namespace {
constexpr int BS = 32;
constexpr int NQ = 1000;
constexpr int NCLS = 100;
constexpr int TPS = 50;
constexpr int TT = BS * TPS;        // 1600
constexpr int NQALL = BS * NQ;      // 32000
constexpr int QTILE = 64;
constexpr int NTILES = 16;          // 16*64 = 1024 covers 1000 (tail tile = 40)
constexpr int NG = TT / 4;          // 400 target groups of 4
}

static __device__ __forceinline__ float clamp01(float x) {
  return fminf(fmaxf(x, 0.0f), 1.0f);
}

// ---- Kernel 1 (fused): focal table (LDS) + cost matrix C + ct transpose ------
__global__ void __launch_bounds__(256) hm_cost(const float* __restrict__ logits,
                                               const float* __restrict__ pred_boxes,
                                               const int* __restrict__ tgt_ids,
                                               const float* __restrict__ tgt_bbox,
                                               float* __restrict__ C,
                                               float* __restrict__ ct) {
  __shared__ float  s_tab[QTILE * NCLS];   // 25.6 KB focal table for this q-tile
  __shared__ float4 s_c2v[NG];             // 6.4 KB  target centers, packed by 4
  __shared__ float4 s_w2v[NG];             // 6.4 KB  target widths
  __shared__ int4   s_id4[NG];             // 6.4 KB  target class ids
  __shared__ float  s_tr[TPS][QTILE + 1];  // 13 KB   own-batch transpose staging
  // total ~57.8 KB -> 2 blocks/CU

  const int bx = blockIdx.x;
  const int b = bx >> 4;
  const int tile = bx & 15;
  const int q0 = tile * QTILE;
  const int nq = min(QTILE, NQ - q0);      // 64 or 40
  const int tid = threadIdx.x;
  const int tlo = b * TPS;

  // Phase A: focal class-cost table for queries [q0, q0+nq)
  for (int i = tid; i < nq * NCLS; i += 256) {
    int ql = i / NCLS, c = i - ql * NCLS;
    float x = logits[((size_t)(b * NQ + q0 + ql)) * NCLS + c];
    float p = 1.0f / (1.0f + expf(-x));
    float neg = 0.75f * (p * p) * (-logf(1.0f - p + 1e-8f));
    float pos = 0.25f * ((1.0f - p) * (1.0f - p)) * (-logf(p + 1e-8f));
    s_tab[i] = pos - neg;
  }
  // Phase B: stage targets (packed float4 groups)
  for (int t = tid; t < TT; t += 256) {
    ((float*)s_c2v)[t] = tgt_bbox[2 * t];
    ((float*)s_w2v)[t] = tgt_bbox[2 * t + 1];
    ((int*)s_id4)[t] = tgt_ids[t];
  }
  __syncthreads();

  // Phase C: compute C rows for this tile; capture own-batch slice into s_tr
  const int nwork = nq * NG;
  for (int w = tid; w < nwork; w += 256) {
    int ql = w / NG;
    int g = w - ql * NG;
    int gq = b * NQ + q0 + ql;
    float c1 = pred_boxes[2 * gq], w1 = pred_boxes[2 * gq + 1];
    float s1 = clamp01(c1 - 0.5f * w1);
    float e1 = clamp01(c1 + 0.5f * w1);
    float len1 = e1 - s1;
    float4 c2 = s_c2v[g];
    float4 w2 = s_w2v[g];
    int4 id = s_id4[g];
    const float* c2p = &c2.x;
    const float* w2p = &w2.x;
    const int* idp = &id.x;
    float4 o;
    float* op = &o.x;
    #pragma unroll
    for (int kk = 0; kk < 4; ++kk) {
      float C2 = c2p[kk], W2 = w2p[kk];
      float cb = fabsf(c1 - C2) + fabsf(w1 - W2);
      float S2 = clamp01(C2 - 0.5f * W2);
      float E2 = clamp01(C2 + 0.5f * W2);
      float inter = fmaxf(fminf(e1, E2) - fmaxf(s1, S2), 0.0f);
      float uni = (len1 + (E2 - S2)) - inter;
      float cg = -(inter * __builtin_amdgcn_rcpf(uni));
      op[kk] = (cb + s_tab[ql * NCLS + idp[kk]]) + cg;
    }
    reinterpret_cast<float4*>(C + (size_t)gq * TT)[g] = o;
    int d = 4 * g - tlo;                   // own-batch window check
    if (d > -4 && d < TPS) {
      #pragma unroll
      for (int kk = 0; kk < 4; ++kk) {
        int tt = d + kk;
        if ((unsigned)tt < (unsigned)TPS) s_tr[tt][ql] = op[kk];
      }
    }
  }
  __syncthreads();

  // Phase D: coalesced write of transposed own-batch slice -> ct[b*50+t][q]
  for (int i2 = tid; i2 < TPS * nq; i2 += 256) {
    int ttt = i2 / nq, qq = i2 - ttt * nq;
    ct[(size_t)(tlo + ttt) * NQ + q0 + qq] = s_tr[ttt][qq];
  }
}

// ---- Kernel 2: per-row min + argmin over ct (1600 rows x 1000 cols) ----------
__global__ void __launch_bounds__(64) hm_rowmin(const float* __restrict__ ct,
                                                float* __restrict__ rmin,
                                                int* __restrict__ rarg) {
  int r = blockIdx.x;
  int lane = threadIdx.x;
  const float* row = ct + (size_t)r * NQ;
  float bv = 1e30f;
  int bj = 0x7fffffff;
  #pragma unroll
  for (int k = 0; k < 16; ++k) {
    int idx = lane + (k << 6);
    if (idx > NQ - 1) idx = NQ - 1;        // duplicate 999: same (val, j) -> harmless
    float c = row[idx];
    int j = idx + 1;                       // 1-indexed column
    if (c < bv || (c == bv && j < bj)) { bv = c; bj = j; }
  }
  #pragma unroll
  for (int off = 32; off; off >>= 1) {
    float ov = __shfl_xor(bv, off);
    int oj = __shfl_xor(bj, off);
    if (ov < bv || (ov == bv && oj < bj)) { bv = ov; bj = oj; }
  }
  if (lane == 0) { rmin[r] = bv; rarg[r] = bj; }
}

// ---- Kernel 3: warm-started Jonker-Volgenant, one wave per batch -------------
// Admissible dual warm start (u[i]=row min, v=0, greedy argmin matching) + the
// proven exact JV phase for the ~1-2 unmatched rows. Optimal assignment is
// unique for continuous random costs -> identical to the reference result.
__global__ void __launch_bounds__(64) hm_lsa(const float* __restrict__ ct,
                                             const float* __restrict__ rmin,
                                             const int* __restrict__ rarg,
                                             float* __restrict__ out_idx) {
  __shared__ double u[TPS + 1];
  __shared__ int p[NQ + 1];
  __shared__ int way[NQ + 1];
  __shared__ int claim[NQ + 1];
  __shared__ int s_unm[TPS];
  __shared__ int s_nu;

  const double INFD = 1e18;
  int b = blockIdx.x;
  int lane = threadIdx.x;
  const float* cbase = ct + (size_t)b * TPS * NQ;

  double v[16], minv[16];
  #pragma unroll
  for (int k = 0; k < 16; ++k) v[k] = 0.0;
  for (int j = lane; j <= NQ; j += 64) { p[j] = 0; way[j] = 0; claim[j] = 0x7fffffff; }
  if (lane < TPS) u[lane + 1] = 0.0;
  if (lane == 63) u[0] = 0.0;
  __syncthreads();

  // greedy warm start
  int i_row = 0, myarg = 0;
  if (lane < TPS) {
    int r = b * TPS + lane;
    i_row = lane + 1;
    myarg = rarg[r];
    u[i_row] = (double)rmin[r];
    atomicMin(&claim[myarg], i_row);
  }
  __syncthreads();
  bool matched = false;
  if (lane < TPS) matched = (claim[myarg] == i_row);
  if (matched) p[myarg] = i_row;
  bool un = (lane < TPS) && !matched;
  unsigned long long mk = __ballot(un);
  if (un) { int pos = __popcll(mk & ((1ull << lane) - 1ull)); s_unm[pos] = i_row; }
  if (lane == 0) s_nu = __popcll(mk);
  __syncthreads();
  int nu = s_nu;

  // exact JV augmenting phases for unmatched rows
  for (int ph = 0; ph < nu; ++ph) {
    int i = s_unm[ph];
    #pragma unroll
    for (int k = 0; k < 16; ++k) minv[k] = INFD;
    unsigned usedmask = 0u;
    if (lane == 0) p[0] = i;
    int j0 = 0;
    int jfin = 0;
    __syncthreads();
    while (true) {
      if (j0 > 0) {
        int kk = (j0 - 1) >> 6, ll = (j0 - 1) & 63;
        if (lane == ll) usedmask |= (1u << kk);
      }
      int i0 = p[j0];
      double ui0 = u[i0];
      const float* row = cbase + (size_t)(i0 - 1) * NQ;
      float rv[16];
      #pragma unroll
      for (int k = 0; k < 16; ++k) {
        int idx = lane + (k << 6); if (idx > NQ - 1) idx = NQ - 1;
        rv[k] = row[idx];
      }
      double bv = INFD; int bj = 0x7fffffff;
      #pragma unroll
      for (int k = 0; k < 16; ++k) {
        int j = 1 + lane + (k << 6);
        bool valid = (k < 15) | (lane < 40);
        if (valid && !((usedmask >> k) & 1u)) {
          double cur = ((double)rv[k] - ui0) - v[k];
          if (cur < minv[k]) { minv[k] = cur; way[j] = j0; }
          double mv = minv[k];
          if (mv < bv || (mv == bv && j < bj)) { bv = mv; bj = j; }
        }
      }
      #pragma unroll
      for (int off = 32; off; off >>= 1) {
        double ov = __shfl_xor(bv, off);
        int oj = __shfl_xor(bj, off);
        if (ov < bv || (ov == bv && oj < bj)) { bv = ov; bj = oj; }
      }
      double delta = bv;
      int j1 = bj;
      if (lane == 0) u[i] += delta;
      #pragma unroll
      for (int k = 0; k < 16; ++k) {
        int j = 1 + lane + (k << 6);
        bool valid = (k < 15) | (lane < 40);
        if (!valid) continue;
        if ((usedmask >> k) & 1u) {
          u[p[j]] += delta;            // distinct rows -> race-free
          v[k] -= delta;
        } else {
          minv[k] -= delta;
        }
      }
      __syncthreads();
      if (p[j1] == 0) { jfin = j1; break; }
      j0 = j1;
    }
    __syncthreads();
    if (lane == 0) {
      int j0a = jfin;
      while (j0a != 0) { int jn = way[j0a]; p[j0a] = p[jn]; j0a = jn; }
    }
    __syncthreads();
  }

  // extraction: ascending column order == identity argsort
  float* o = out_idx + b * 2 * TPS;
  int total = 0;
  #pragma unroll
  for (int k = 0; k < 16; ++k) {
    int j = 1 + lane + (k << 6);
    bool valid = (k < 15) | (lane < 40);
    int pj = valid ? p[j] : 0;
    bool m = valid && (pj != 0);
    unsigned long long mask = __ballot(m);
    int pos = total + __popcll(mask & ((1ull << lane) - 1ull));
    if (m) { o[pos] = (float)(j - 1); o[TPS + pos] = (float)(pj - 1); }
    total += __popcll(mask);
  }
}

extern "C" void kernel_launch(void* const* d_in, const int* in_sizes, int n_in,
                              void* d_out, int out_size, void* d_ws, size_t ws_size,
                              hipStream_t stream) {
  const float* logits     = (const float*)d_in[0];  // [32,1000,100]
  const float* pred_boxes = (const float*)d_in[1];  // [32,1000,2]
  const int*   tgt_ids    = (const int*)d_in[2];    // [1600]
  const float* tgt_bbox   = (const float*)d_in[3];  // [1600,2]
  float* out = (float*)d_out;                       // C (51.2M f32) then indices

  float* ct   = (float*)d_ws;                                   // 6.4 MB
  float* rmin = (float*)((char*)d_ws + (size_t)TT * NQ * 4);    // 6.4 KB
  int*   rarg = (int*)((char*)d_ws + (size_t)TT * NQ * 4 + TT * 4);

  hm_cost<<<BS * NTILES, 256, 0, stream>>>(logits, pred_boxes, tgt_ids, tgt_bbox, out, ct);
  hm_rowmin<<<TT, 64, 0, stream>>>(ct, rmin, rarg);
  hm_lsa<<<BS, 64, 0, stream>>>(ct, rmin, rarg, out + (size_t)NQALL * TT);
}

// Round 5
// 283.002 us; speedup vs baseline: 1.7902x; 1.0222x over previous
//
#include <hip/hip_runtime.h>
#include <hip/hip_bf16.h>

namespace {
constexpr int BS = 32;
constexpr int NQ = 1000;
constexpr int NCLS = 100;
constexpr int TPS = 50;
constexpr int TT = BS * TPS;        // 1600
constexpr int NQALL = BS * NQ;      // 32000
constexpr int QTILE = 64;
constexpr int NTILES = 16;          // 16*64 = 1024 covers 1000 (tail tile = 40)
constexpr int NG = TT / 4;          // 400 target groups of 4
}

static __device__ __forceinline__ float clamp01(float x) {
  return fminf(fmaxf(x, 0.0f), 1.0f);
}

// ---- Kernel 1 (fused): focal table (LDS) + cost C + ct transpose + row-min partials
__global__ void __launch_bounds__(256) hm_cost(const float* __restrict__ logits,
                                               const float* __restrict__ pred_boxes,
                                               const int* __restrict__ tgt_ids,
                                               const float* __restrict__ tgt_bbox,
                                               float* __restrict__ C,
                                               float* __restrict__ ct,
                                               float* __restrict__ pmin,
                                               int* __restrict__ parg) {
  __shared__ float  s_tab[QTILE * NCLS];   // 25.6 KB focal table for this q-tile
  __shared__ float4 s_c2v[NG];             // 6.4 KB  target centers, packed by 4
  __shared__ float4 s_w2v[NG];             // 6.4 KB  target widths
  __shared__ int4   s_id4[NG];             // 6.4 KB  target class ids
  __shared__ float  s_tr[TPS][QTILE + 1];  // 13 KB   own-batch transpose staging

  const int bx = blockIdx.x;
  const int b = bx >> 4;
  const int tile = bx & 15;
  const int q0 = tile * QTILE;
  const int nq = min(QTILE, NQ - q0);      // 64 or 40
  const int tid = threadIdx.x;
  const int tlo = b * TPS;

  // Phase A: focal class-cost table for queries [q0, q0+nq)
  for (int i = tid; i < nq * NCLS; i += 256) {
    int ql = i / NCLS, c = i - ql * NCLS;
    float x = logits[((size_t)(b * NQ + q0 + ql)) * NCLS + c];
    float p = 1.0f / (1.0f + expf(-x));
    float neg = 0.75f * (p * p) * (-logf(1.0f - p + 1e-8f));
    float pos = 0.25f * ((1.0f - p) * (1.0f - p)) * (-logf(p + 1e-8f));
    s_tab[i] = pos - neg;
  }
  // Phase B: stage targets (packed float4 groups)
  for (int t = tid; t < TT; t += 256) {
    ((float*)s_c2v)[t] = tgt_bbox[2 * t];
    ((float*)s_w2v)[t] = tgt_bbox[2 * t + 1];
    ((int*)s_id4)[t] = tgt_ids[t];
  }
  __syncthreads();

  // Phase C: compute C rows for this tile; capture own-batch slice into s_tr
  const int nwork = nq * NG;
  for (int w = tid; w < nwork; w += 256) {
    int ql = w / NG;
    int g = w - ql * NG;
    int gq = b * NQ + q0 + ql;
    float c1 = pred_boxes[2 * gq], w1 = pred_boxes[2 * gq + 1];
    float s1 = clamp01(c1 - 0.5f * w1);
    float e1 = clamp01(c1 + 0.5f * w1);
    float len1 = e1 - s1;
    float4 c2 = s_c2v[g];
    float4 w2 = s_w2v[g];
    int4 id = s_id4[g];
    const float* c2p = &c2.x;
    const float* w2p = &w2.x;
    const int* idp = &id.x;
    float4 o;
    float* op = &o.x;
    #pragma unroll
    for (int kk = 0; kk < 4; ++kk) {
      float C2 = c2p[kk], W2 = w2p[kk];
      float cb = fabsf(c1 - C2) + fabsf(w1 - W2);
      float S2 = clamp01(C2 - 0.5f * W2);
      float E2 = clamp01(C2 + 0.5f * W2);
      float inter = fmaxf(fminf(e1, E2) - fmaxf(s1, S2), 0.0f);
      float uni = (len1 + (E2 - S2)) - inter;
      float cg = -(inter * __builtin_amdgcn_rcpf(uni));
      op[kk] = (cb + s_tab[ql * NCLS + idp[kk]]) + cg;
    }
    reinterpret_cast<float4*>(C + (size_t)gq * TT)[g] = o;
    int d = 4 * g - tlo;                   // own-batch window check
    if (d > -4 && d < TPS) {
      #pragma unroll
      for (int kk = 0; kk < 4; ++kk) {
        int tt = d + kk;
        if ((unsigned)tt < (unsigned)TPS) s_tr[tt][ql] = op[kk];
      }
    }
  }
  __syncthreads();

  // Phase D: coalesced write of transposed own-batch slice -> ct[b*50+t][q]
  for (int i2 = tid; i2 < TPS * nq; i2 += 256) {
    int ttt = i2 / nq, qq = i2 - ttt * nq;
    ct[(size_t)(tlo + ttt) * NQ + q0 + qq] = s_tr[ttt][qq];
  }
  // Phase E: per-tile row-min partials over s_tr (threads 0..49, serial over nq)
  if (tid < TPS) {
    float bv = 1e30f;
    int bj = 0x7fffffff;
    for (int qq = 0; qq < nq; ++qq) {
      float c = s_tr[tid][qq];
      if (c < bv) { bv = c; bj = q0 + qq + 1; }   // strict < keeps first index
    }
    pmin[(size_t)(tlo + tid) * NTILES + tile] = bv;
    parg[(size_t)(tlo + tid) * NTILES + tile] = bj;
  }
}

// ---- Kernel 2: warm-started Jonker-Volgenant, one wave per batch -------------
// Reduce 16 row-min partials/row, greedy admissible warm start (u[i]=row min,
// v=0, argmin claim), then exact JV phases for the ~1-2 unmatched rows.
// Optimal assignment is unique for continuous random costs -> matches reference.
__global__ void __launch_bounds__(64) hm_lsa(const float* __restrict__ ct,
                                             const float* __restrict__ pmin,
                                             const int* __restrict__ parg,
                                             float* __restrict__ out_idx) {
  __shared__ double u[TPS + 1];
  __shared__ int p[NQ + 1];
  __shared__ int way[NQ + 1];
  __shared__ int claim[NQ + 1];
  __shared__ int s_unm[TPS];
  __shared__ int s_nu;

  const double INFD = 1e18;
  int b = blockIdx.x;
  int lane = threadIdx.x;
  const float* cbase = ct + (size_t)b * TPS * NQ;

  double v[16], minv[16];
  #pragma unroll
  for (int k = 0; k < 16; ++k) v[k] = 0.0;
  for (int j = lane; j <= NQ; j += 64) { p[j] = 0; way[j] = 0; claim[j] = 0x7fffffff; }
  if (lane < TPS) u[lane + 1] = 0.0;
  if (lane == 63) u[0] = 0.0;
  __syncthreads();

  // reduce row-min partials (lane < 50: serial over 16 tile partials)
  int i_row = 0, myarg = 0;
  if (lane < TPS) {
    int r = b * TPS + lane;
    float bv = 1e30f;
    int bj = 0x7fffffff;
    #pragma unroll
    for (int t = 0; t < NTILES; ++t) {
      float c = pmin[(size_t)r * NTILES + t];
      int j = parg[(size_t)r * NTILES + t];
      if (c < bv || (c == bv && j < bj)) { bv = c; bj = j; }
    }
    i_row = lane + 1;
    myarg = bj;
    u[i_row] = (double)bv;
    atomicMin(&claim[myarg], i_row);
  }
  __syncthreads();
  bool matched = false;
  if (lane < TPS) matched = (claim[myarg] == i_row);
  if (matched) p[myarg] = i_row;
  bool un = (lane < TPS) && !matched;
  unsigned long long mk = __ballot(un);
  if (un) { int pos = __popcll(mk & ((1ull << lane) - 1ull)); s_unm[pos] = i_row; }
  if (lane == 0) s_nu = __popcll(mk);
  __syncthreads();
  int nu = s_nu;

  // exact JV augmenting phases for unmatched rows
  for (int ph = 0; ph < nu; ++ph) {
    int i = s_unm[ph];
    #pragma unroll
    for (int k = 0; k < 16; ++k) minv[k] = INFD;
    unsigned usedmask = 0u;
    if (lane == 0) p[0] = i;
    int j0 = 0;
    int jfin = 0;
    __syncthreads();
    while (true) {
      if (j0 > 0) {
        int kk = (j0 - 1) >> 6, ll = (j0 - 1) & 63;
        if (lane == ll) usedmask |= (1u << kk);
      }
      int i0 = p[j0];
      double ui0 = u[i0];
      const float* row = cbase + (size_t)(i0 - 1) * NQ;
      float rv[16];
      #pragma unroll
      for (int k = 0; k < 16; ++k) {
        int idx = lane + (k << 6); if (idx > NQ - 1) idx = NQ - 1;
        rv[k] = row[idx];
      }
      double bv = INFD; int bj = 0x7fffffff;
      #pragma unroll
      for (int k = 0; k < 16; ++k) {
        int j = 1 + lane + (k << 6);
        bool valid = (k < 15) | (lane < 40);
        if (valid && !((usedmask >> k) & 1u)) {
          double cur = ((double)rv[k] - ui0) - v[k];
          if (cur < minv[k]) { minv[k] = cur; way[j] = j0; }
          double mv = minv[k];
          if (mv < bv || (mv == bv && j < bj)) { bv = mv; bj = j; }
        }
      }
      #pragma unroll
      for (int off = 32; off; off >>= 1) {
        double ov = __shfl_xor(bv, off);
        int oj = __shfl_xor(bj, off);
        if (ov < bv || (ov == bv && oj < bj)) { bv = ov; bj = oj; }
      }
      double delta = bv;
      int j1 = bj;
      if (lane == 0) u[i] += delta;
      #pragma unroll
      for (int k = 0; k < 16; ++k) {
        int j = 1 + lane + (k << 6);
        bool valid = (k < 15) | (lane < 40);
        if (!valid) continue;
        if ((usedmask >> k) & 1u) {
          u[p[j]] += delta;            // distinct rows -> race-free
          v[k] -= delta;
        } else {
          minv[k] -= delta;
        }
      }
      __syncthreads();
      if (p[j1] == 0) { jfin = j1; break; }
      j0 = j1;
    }
    __syncthreads();
    if (lane == 0) {
      int j0a = jfin;
      while (j0a != 0) { int jn = way[j0a]; p[j0a] = p[jn]; j0a = jn; }
    }
    __syncthreads();
  }

  // extraction: ascending column order == identity argsort
  float* o = out_idx + b * 2 * TPS;
  int total = 0;
  #pragma unroll
  for (int k = 0; k < 16; ++k) {
    int j = 1 + lane + (k << 6);
    bool valid = (k < 15) | (lane < 40);
    int pj = valid ? p[j] : 0;
    bool m = valid && (pj != 0);
    unsigned long long mask = __ballot(m);
    int pos = total + __popcll(mask & ((1ull << lane) - 1ull));
    if (m) { o[pos] = (float)(j - 1); o[TPS + pos] = (float)(pj - 1); }
    total += __popcll(mask);
  }
}

extern "C" void kernel_launch(void* const* d_in, const int* in_sizes, int n_in,
                              void* d_out, int out_size, void* d_ws, size_t ws_size,
                              hipStream_t stream) {
  const float* logits     = (const float*)d_in[0];  // [32,1000,100]
  const float* pred_boxes = (const float*)d_in[1];  // [32,1000,2]
  const int*   tgt_ids    = (const int*)d_in[2];    // [1600]
  const float* tgt_bbox   = (const float*)d_in[3];  // [1600,2]
  float* out = (float*)d_out;                       // C (51.2M f32) then indices

  char* ws = (char*)d_ws;
  float* ct   = (float*)ws;                                  // 6.4 MB
  float* pmin = (float*)(ws + (size_t)TT * NQ * 4);          // 102.4 KB
  int*   parg = (int*)(ws + (size_t)TT * NQ * 4 + (size_t)TT * NTILES * 4);

  hm_cost<<<BS * NTILES, 256, 0, stream>>>(logits, pred_boxes, tgt_ids, tgt_bbox,
                                           out, ct, pmin, parg);
  hm_lsa<<<BS, 64, 0, stream>>>(ct, pmin, parg, out + (size_t)NQALL * TT);
}